// Round 1
// baseline (900.937 us; speedup 1.0000x reference)
//
#include <hip/hip_runtime.h>
#include <math.h>

// Sinkhorn via potentials: log_m after any number of alternating row/col
// normalizations is m + u[i] + v[j] on the valid region. Each half-iteration
// is a logsumexp reduction over the 256MB matrix; matrix is never rewritten.
//
// Workspace layout (d_ws): u = B*N floats, then v = B*M floats (512 KB total).

#define NEGINF (-__builtin_inff())

__device__ __forceinline__ float wave_max64(float v) {
#pragma unroll
    for (int o = 32; o > 0; o >>= 1) v = fmaxf(v, __shfl_xor(v, o, 64));
    return v;
}
__device__ __forceinline__ float wave_sum64(float v) {
#pragma unroll
    for (int o = 32; o > 0; o >>= 1) v += __shfl_xor(v, o, 64);
    return v;
}

// One wave per row. Row = 1024 floats = 64 lanes x 16 elems (4x float4).
// u[b,i] = -(logsumexp over j<ncols of m[b,i,j] + (FIRST ? 0 : v[b,j]))
template <int FIRST>
__global__ __launch_bounds__(256) void row_pass(
    const float* __restrict__ m, const int* __restrict__ nrows,
    const int* __restrict__ ncols, const float* __restrict__ v,
    float* __restrict__ u, int N, int M) {
    const int b = blockIdx.y;
    const int row = blockIdx.x * 4 + (threadIdx.x >> 6);
    const int lane = threadIdx.x & 63;
    const int nr = nrows[b];
    if (row >= nr) return;
    const int nc = ncols[b];
    if (nc == 0) {  // no valid columns: u unused downstream, keep it finite
        if (lane == 0) u[(size_t)b * N + row] = 0.f;
        return;
    }
    const float* rowp = m + ((size_t)b * N + row) * M;
    const float* vp = v + (size_t)b * M;

    float x[16];
#pragma unroll
    for (int k = 0; k < 4; ++k) {
        const int j = lane * 4 + k * 256;  // 64 lanes x 16B contiguous per k
        const float4 mv = *reinterpret_cast<const float4*>(rowp + j);
        float4 xv;
        if (FIRST) {
            xv = mv;
        } else {
            const float4 vv = *reinterpret_cast<const float4*>(vp + j);
            xv = make_float4(mv.x + vv.x, mv.y + vv.y, mv.z + vv.z, mv.w + vv.w);
        }
        x[4 * k + 0] = (j + 0 < nc) ? xv.x : NEGINF;
        x[4 * k + 1] = (j + 1 < nc) ? xv.y : NEGINF;
        x[4 * k + 2] = (j + 2 < nc) ? xv.z : NEGINF;
        x[4 * k + 3] = (j + 3 < nc) ? xv.w : NEGINF;
    }
    float mx = x[0];
#pragma unroll
    for (int e = 1; e < 16; ++e) mx = fmaxf(mx, x[e]);
    mx = wave_max64(mx);  // finite: nc>0 guarantees >=1 valid element
    float s = 0.f;
#pragma unroll
    for (int e = 0; e < 16; ++e) s += __expf(x[e] - mx);  // exp(-inf)=0 for masked
    s = wave_sum64(s);
    if (lane == 0) u[(size_t)b * N + row] = -(mx + __logf(s));
}

// Block: 1024 threads = 64 col-groups (x4 cols via float4) x 16 row-groups.
// Each block covers 256 columns of one batch; online logsumexp down the rows,
// then LDS combine across the 16 row-groups.
// v[b,j] = -(logsumexp over i<nrows of m[b,i,j] + u[b,i])
__global__ __launch_bounds__(1024) void col_pass(
    const float* __restrict__ m, const int* __restrict__ nrows,
    const float* __restrict__ u, float* __restrict__ v, int N, int M) {
    const int b = blockIdx.y;
    const int cg = threadIdx.x & 63;   // column group within 256-col chunk
    const int rg = threadIdx.x >> 6;   // row group 0..15
    const int col0 = blockIdx.x * 256 + cg * 4;
    const int nr = nrows[b];
    const float* mb = m + (size_t)b * N * M + col0;
    const float* ub = u + (size_t)b * N;

    float4 mx = make_float4(NEGINF, NEGINF, NEGINF, NEGINF);
    float4 s = make_float4(0.f, 0.f, 0.f, 0.f);
    for (int i = rg; i < nr; i += 16) {
        const float ui = ub[i];  // finite for all i<nr (row_pass guarantees)
        const float4 mv = *reinterpret_cast<const float4*>(mb + (size_t)i * M);
        const float4 xv = make_float4(mv.x + ui, mv.y + ui, mv.z + ui, mv.w + ui);
        float4 nm = make_float4(fmaxf(mx.x, xv.x), fmaxf(mx.y, xv.y),
                                fmaxf(mx.z, xv.z), fmaxf(mx.w, xv.w));
        // first iter: mx=-inf, nm finite -> exp(-inf)=0, no NaN
        s.x = s.x * __expf(mx.x - nm.x) + __expf(xv.x - nm.x);
        s.y = s.y * __expf(mx.y - nm.y) + __expf(xv.y - nm.y);
        s.z = s.z * __expf(mx.z - nm.z) + __expf(xv.z - nm.z);
        s.w = s.w * __expf(mx.w - nm.w) + __expf(xv.w - nm.w);
        mx = nm;
    }

    __shared__ float sm[16][64][4];  // 16KB
    __shared__ float ss[16][64][4];  // 16KB
    sm[rg][cg][0] = mx.x; sm[rg][cg][1] = mx.y; sm[rg][cg][2] = mx.z; sm[rg][cg][3] = mx.w;
    ss[rg][cg][0] = s.x;  ss[rg][cg][1] = s.y;  ss[rg][cg][2] = s.z;  ss[rg][cg][3] = s.w;
    __syncthreads();

    if (threadIdx.x < 64) {
        const int c = threadIdx.x;
        float cm[4], cs[4];
#pragma unroll
        for (int e = 0; e < 4; ++e) { cm[e] = sm[0][c][e]; cs[e] = ss[0][c][e]; }
        for (int r = 1; r < 16; ++r) {
#pragma unroll
            for (int e = 0; e < 4; ++e) {
                const float m2 = sm[r][c][e], s2 = ss[r][c][e];
                const float nm = fmaxf(cm[e], m2);
                cs[e] = cs[e] * __expf(cm[e] - nm) + s2 * __expf(m2 - nm);
                cm[e] = nm;
            }
        }
        float4 out;
        out.x = -(cm[0] + __logf(cs[0]));
        out.y = -(cm[1] + __logf(cs[1]));
        out.z = -(cm[2] + __logf(cs[2]));
        out.w = -(cm[3] + __logf(cs[3]));
        // nr==0 gives NaN here; those batches are fully masked in final_pass
        *reinterpret_cast<float4*>(v + (size_t)b * M + blockIdx.x * 256 + c * 4) = out;
    }
}

// out[b,i,j] = (i<nrows && j<ncols) ? exp(m + u[i] + v[j]) : 0
__global__ __launch_bounds__(256) void final_pass(
    const float* __restrict__ m, const int* __restrict__ nrows,
    const int* __restrict__ ncols, const float* __restrict__ u,
    const float* __restrict__ v, float* __restrict__ out, int N, int M) {
    const int b = blockIdx.y;
    const size_t off = ((size_t)blockIdx.x * 256 + threadIdx.x) * 4;  // in-batch
    const int i = (int)(off / (size_t)M);
    const int j = (int)(off % (size_t)M);  // j..j+3 same row (M multiple of 4)
    const int nr = nrows[b];
    const int nc = ncols[b];
    const size_t g = (size_t)b * N * M + off;
    float4 r = make_float4(0.f, 0.f, 0.f, 0.f);
    if (i < nr) {
        const float4 mv = *reinterpret_cast<const float4*>(m + g);
        const float ui = u[(size_t)b * N + i];
        const float4 vv = *reinterpret_cast<const float4*>(v + (size_t)b * M + j);
        r.x = (j + 0 < nc) ? __expf(mv.x + ui + vv.x) : 0.f;
        r.y = (j + 1 < nc) ? __expf(mv.y + ui + vv.y) : 0.f;
        r.z = (j + 2 < nc) ? __expf(mv.z + ui + vv.z) : 0.f;
        r.w = (j + 3 < nc) ? __expf(mv.w + ui + vv.w) : 0.f;
    }
    *reinterpret_cast<float4*>(out + g) = r;
}

extern "C" void kernel_launch(void* const* d_in, const int* in_sizes, int n_in,
                              void* d_out, int out_size, void* d_ws, size_t ws_size,
                              hipStream_t stream) {
    const float* m = (const float*)d_in[0];
    const int* nrows = (const int*)d_in[1];
    const int* ncols = (const int*)d_in[2];
    const int B = in_sizes[1];
    const int N = 1024, M = 1024;

    float* u = (float*)d_ws;             // B*N floats
    float* v = u + (size_t)B * N;        // B*M floats
    float* out = (float*)d_out;

    const dim3 rgrid(N / 4, B), rblk(256);
    const dim3 cgrid(M / 256, B), cblk(1024);

    row_pass<1><<<rgrid, rblk, 0, stream>>>(m, nrows, ncols, v, u, N, M);
    col_pass<<<cgrid, cblk, 0, stream>>>(m, nrows, u, v, N, M);
    for (int t = 1; t < 10; ++t) {
        row_pass<0><<<rgrid, rblk, 0, stream>>>(m, nrows, ncols, v, u, N, M);
        col_pass<<<cgrid, cblk, 0, stream>>>(m, nrows, u, v, N, M);
    }
    final_pass<<<dim3((N * M / 4) / 256, B), 256, 0, stream>>>(m, nrows, ncols, u, v, out, N, M);
}

// Round 2
// 872.998 us; speedup vs baseline: 1.0320x; 1.0320x over previous
//
#include <hip/hip_runtime.h>
#include <math.h>

// Sinkhorn via potentials: log_m after any number of alternating row/col
// normalizations is m + u[i] + v[j] on the valid region. Each half-iteration
// is a logsumexp reduction; matrix never rewritten.
//
// R2: iteration passes read an fp16 copy of m (128 MB instead of 256 MB).
// The fp16 copy is built by the first row pass (which reads fp32 m anyway)
// and lives in the first half of d_out (scratch until final_pass overwrites).
// Final pass uses fp32 m, so output error comes only from u+v (~1e-3).
//
// Workspace (d_ws): u = B*N floats, v = B*M floats (512 KB).

#define NEGINF (-__builtin_inff())

typedef _Float16 h16;
struct alignas(8) h4 { h16 x, y, z, w; };

__device__ __forceinline__ float wave_max64(float v) {
#pragma unroll
    for (int o = 32; o > 0; o >>= 1) v = fmaxf(v, __shfl_xor(v, o, 64));
    return v;
}
__device__ __forceinline__ float wave_sum64(float v) {
#pragma unroll
    for (int o = 32; o > 0; o >>= 1) v += __shfl_xor(v, o, 64);
    return v;
}

// First row pass: reads fp32 m, emits fp16 copy, computes
// u[b,i] = -(logsumexp over j<ncols of m[b,i,j]). One wave per row.
__global__ __launch_bounds__(256) void row_first(
    const float* __restrict__ m, const int* __restrict__ nrows,
    const int* __restrict__ ncols, float* __restrict__ u,
    h16* __restrict__ mh, int N, int M) {
    const int b = blockIdx.y;
    const int row = blockIdx.x * 4 + (threadIdx.x >> 6);
    const int lane = threadIdx.x & 63;
    const int nr = nrows[b];
    if (row >= nr) return;  // rows >= nr never converted, never read later
    const int nc = ncols[b];
    const float* rowp = m + ((size_t)b * N + row) * M;
    h16* rowh = mh + ((size_t)b * N + row) * M;

    float x[16];
#pragma unroll
    for (int k = 0; k < 4; ++k) {
        const int j = lane * 4 + k * 256;  // 64 lanes x 16B contiguous
        const float4 mv = *reinterpret_cast<const float4*>(rowp + j);
        h4 hv;
        hv.x = (h16)mv.x; hv.y = (h16)mv.y; hv.z = (h16)mv.z; hv.w = (h16)mv.w;
        *reinterpret_cast<h4*>(rowh + j) = hv;  // always convert rows < nr
        x[4 * k + 0] = (j + 0 < nc) ? mv.x : NEGINF;
        x[4 * k + 1] = (j + 1 < nc) ? mv.y : NEGINF;
        x[4 * k + 2] = (j + 2 < nc) ? mv.z : NEGINF;
        x[4 * k + 3] = (j + 3 < nc) ? mv.w : NEGINF;
    }
    if (nc == 0) {  // no valid columns: keep u finite; outputs masked anyway
        if (lane == 0) u[(size_t)b * N + row] = 0.f;
        return;
    }
    float mx = x[0];
#pragma unroll
    for (int e = 1; e < 16; ++e) mx = fmaxf(mx, x[e]);
    mx = wave_max64(mx);
    float s = 0.f;
#pragma unroll
    for (int e = 0; e < 16; ++e) s += __expf(x[e] - mx);
    s = wave_sum64(s);
    if (lane == 0) u[(size_t)b * N + row] = -(mx + __logf(s));
}

// Steady-state row pass on fp16 m:
// u[b,i] = -(logsumexp over j<ncols of m[b,i,j] + v[b,j])
__global__ __launch_bounds__(256) void row_pass(
    const h16* __restrict__ mh, const int* __restrict__ nrows,
    const int* __restrict__ ncols, const float* __restrict__ v,
    float* __restrict__ u, int N, int M) {
    const int b = blockIdx.y;
    const int row = blockIdx.x * 4 + (threadIdx.x >> 6);
    const int lane = threadIdx.x & 63;
    const int nr = nrows[b];
    if (row >= nr) return;
    const int nc = ncols[b];
    if (nc == 0) {
        if (lane == 0) u[(size_t)b * N + row] = 0.f;
        return;
    }
    const h16* rowp = mh + ((size_t)b * N + row) * M;
    const float* vp = v + (size_t)b * M;

    float x[16];
#pragma unroll
    for (int k = 0; k < 4; ++k) {
        const int j = lane * 4 + k * 256;
        const h4 hv = *reinterpret_cast<const h4*>(rowp + j);
        const float4 vv = *reinterpret_cast<const float4*>(vp + j);
        x[4 * k + 0] = (j + 0 < nc) ? (float)hv.x + vv.x : NEGINF;
        x[4 * k + 1] = (j + 1 < nc) ? (float)hv.y + vv.y : NEGINF;
        x[4 * k + 2] = (j + 2 < nc) ? (float)hv.z + vv.z : NEGINF;
        x[4 * k + 3] = (j + 3 < nc) ? (float)hv.w + vv.w : NEGINF;
    }
    float mx = x[0];
#pragma unroll
    for (int e = 1; e < 16; ++e) mx = fmaxf(mx, x[e]);
    mx = wave_max64(mx);
    float s = 0.f;
#pragma unroll
    for (int e = 0; e < 16; ++e) s += __expf(x[e] - mx);
    s = wave_sum64(s);
    if (lane == 0) u[(size_t)b * N + row] = -(mx + __logf(s));
}

// Col pass on fp16 m. Block: 1024 thr = 64 col-groups (x4 cols) x 16 row-grps.
// v[b,j] = -(logsumexp over i<nrows of m[b,i,j] + u[b,i])
__global__ __launch_bounds__(1024) void col_pass(
    const h16* __restrict__ mh, const int* __restrict__ nrows,
    const float* __restrict__ u, float* __restrict__ v, int N, int M) {
    const int b = blockIdx.y;
    const int cg = threadIdx.x & 63;
    const int rg = threadIdx.x >> 6;
    const int col0 = blockIdx.x * 256 + cg * 4;
    const int nr = nrows[b];
    const h16* mb = mh + (size_t)b * N * M + col0;
    const float* ub = u + (size_t)b * N;

    float4 mx = make_float4(NEGINF, NEGINF, NEGINF, NEGINF);
    float4 s = make_float4(0.f, 0.f, 0.f, 0.f);
    for (int i = rg; i < nr; i += 16) {
        const float ui = ub[i];
        const h4 hv = *reinterpret_cast<const h4*>(mb + (size_t)i * M);
        const float4 xv = make_float4((float)hv.x + ui, (float)hv.y + ui,
                                      (float)hv.z + ui, (float)hv.w + ui);
        float4 nm = make_float4(fmaxf(mx.x, xv.x), fmaxf(mx.y, xv.y),
                                fmaxf(mx.z, xv.z), fmaxf(mx.w, xv.w));
        s.x = s.x * __expf(mx.x - nm.x) + __expf(xv.x - nm.x);
        s.y = s.y * __expf(mx.y - nm.y) + __expf(xv.y - nm.y);
        s.z = s.z * __expf(mx.z - nm.z) + __expf(xv.z - nm.z);
        s.w = s.w * __expf(mx.w - nm.w) + __expf(xv.w - nm.w);
        mx = nm;
    }

    __shared__ float sm[16][64][4];  // 16KB
    __shared__ float ss[16][64][4];  // 16KB
    sm[rg][cg][0] = mx.x; sm[rg][cg][1] = mx.y; sm[rg][cg][2] = mx.z; sm[rg][cg][3] = mx.w;
    ss[rg][cg][0] = s.x;  ss[rg][cg][1] = s.y;  ss[rg][cg][2] = s.z;  ss[rg][cg][3] = s.w;
    __syncthreads();

    if (threadIdx.x < 64) {
        const int c = threadIdx.x;
        float cm[4], cs[4];
#pragma unroll
        for (int e = 0; e < 4; ++e) { cm[e] = sm[0][c][e]; cs[e] = ss[0][c][e]; }
        for (int r = 1; r < 16; ++r) {
#pragma unroll
            for (int e = 0; e < 4; ++e) {
                const float m2 = sm[r][c][e], s2 = ss[r][c][e];
                const float nm = fmaxf(cm[e], m2);
                cs[e] = cs[e] * __expf(cm[e] - nm) + s2 * __expf(m2 - nm);
                cm[e] = nm;
            }
        }
        float4 out;
        out.x = -(cm[0] + __logf(cs[0]));
        out.y = -(cm[1] + __logf(cs[1]));
        out.z = -(cm[2] + __logf(cs[2]));
        out.w = -(cm[3] + __logf(cs[3]));
        // nr==0 -> inf/NaN here; those batches fully masked in final_pass
        *reinterpret_cast<float4*>(v + (size_t)b * M + blockIdx.x * 256 + c * 4) = out;
    }
}

// out[b,i,j] = (i<nrows && j<ncols) ? exp(m + u[i] + v[j]) : 0   (fp32 m)
__global__ __launch_bounds__(256) void final_pass(
    const float* __restrict__ m, const int* __restrict__ nrows,
    const int* __restrict__ ncols, const float* __restrict__ u,
    const float* __restrict__ v, float* __restrict__ out, int N, int M) {
    const int b = blockIdx.y;
    const size_t off = ((size_t)blockIdx.x * 256 + threadIdx.x) * 4;
    const int i = (int)(off / (size_t)M);
    const int j = (int)(off % (size_t)M);
    const int nr = nrows[b];
    const int nc = ncols[b];
    const size_t g = (size_t)b * N * M + off;
    float4 r = make_float4(0.f, 0.f, 0.f, 0.f);
    if (i < nr) {
        const float4 mv = *reinterpret_cast<const float4*>(m + g);
        const float ui = u[(size_t)b * N + i];
        const float4 vv = *reinterpret_cast<const float4*>(v + (size_t)b * M + j);
        r.x = (j + 0 < nc) ? __expf(mv.x + ui + vv.x) : 0.f;
        r.y = (j + 1 < nc) ? __expf(mv.y + ui + vv.y) : 0.f;
        r.z = (j + 2 < nc) ? __expf(mv.z + ui + vv.z) : 0.f;
        r.w = (j + 3 < nc) ? __expf(mv.w + ui + vv.w) : 0.f;
    }
    *reinterpret_cast<float4*>(out + g) = r;
}

extern "C" void kernel_launch(void* const* d_in, const int* in_sizes, int n_in,
                              void* d_out, int out_size, void* d_ws, size_t ws_size,
                              hipStream_t stream) {
    const float* m = (const float*)d_in[0];
    const int* nrows = (const int*)d_in[1];
    const int* ncols = (const int*)d_in[2];
    const int B = in_sizes[1];
    const int N = 1024, M = 1024;

    float* u = (float*)d_ws;          // B*N floats
    float* v = u + (size_t)B * N;     // B*M floats
    float* out = (float*)d_out;
    h16* mh = (h16*)d_out;            // fp16 m copy: first 128 MB of d_out,
                                      // valid until final_pass overwrites it

    const dim3 rgrid(N / 4, B), rblk(256);
    const dim3 cgrid(M / 256, B), cblk(1024);

    row_first<<<rgrid, rblk, 0, stream>>>(m, nrows, ncols, u, mh, N, M);
    col_pass<<<cgrid, cblk, 0, stream>>>(mh, nrows, u, v, N, M);
    for (int t = 1; t < 10; ++t) {
        row_pass<<<rgrid, rblk, 0, stream>>>(mh, nrows, ncols, v, u, N, M);
        col_pass<<<cgrid, cblk, 0, stream>>>(mh, nrows, u, v, N, M);
    }
    final_pass<<<dim3((N * M / 4) / 256, B), 256, 0, stream>>>(m, nrows, ncols, u, v, out, N, M);
}